// Round 5
// baseline (108.037 us; speedup 1.0000x reference)
//
#include <hip/hip_runtime.h>

// SecConv2d over Z_{2^32} via i8 MFMA, 4-chain biased-operand scheme (exact).
//   s(x) = x_byte - 128 per limb  => X = s(al) + 256*s(ah) + 32896
//   s(w) likewise                 => W = s0 + 256*s1 + 32896
//   out = P00 + (P01+P10)<<8 + P11<<16 + 32896*Q[p] + K[k]   (mod 2^32)
//   Q = 3x3 box sum of S[p], S[p] = sum_c (X_true - 32896) (border cells are
//   bytes 0x80 == s=-128 -> uniformly "interior with x=0", exact).
//
// R14 == R13 resubmitted (previous round was an infra failure, no HW result).
// R13 = R11 chunked double-buffered pipeline (7 chunks of 8 out-cols with
// 10 halo cols; wave = one 16-k tile over all 4 output rows, wf = 72 VGPR;
// balanced pack = 240 quarter-pixel tasks) with the R10-era batch-stride
// typo fixed: 64*3136 = 200704 (was hand-written 201728 -> every n>=1 block
// read shifted input; caused the three identical absmax=2^32 failures).
// Plus T5 s_setprio around the MFMA cluster.

typedef int v4i __attribute__((ext_vector_type(4)));

#define LCOL 144               // LDS col stride (128 B payload + 16 pad)
#define CROW (10 * LCOL)       // 1440 B per halo row within a chunk
#define CBUF (6 * CROW)        // 8640 B per chunk buffer

__device__ __align__(16) unsigned char g_wb[2 * 9 * 64 * 64];
__device__ unsigned g_off[64];

static __device__ __forceinline__ unsigned bsum(unsigned v, unsigned acc) {
#if __has_builtin(__builtin_amdgcn_sad_u8)
    return __builtin_amdgcn_sad_u8(v, 0u, acc);
#else
    return acc + (v & 0xFFu) + ((v >> 8) & 0xFFu) + ((v >> 16) & 0xFFu) + (v >> 24);
#endif
}

__global__ __launch_bounds__(256) void packw(const int* __restrict__ w,
                                             const int* __restrict__ bias) {
    int blk = blockIdx.x;
    if (blk < 144) {
        int i = blk * 256 + threadIdx.x;        // [k][c][t] flat, 36864
        if (i >= 64 * 64 * 9) return;
        int k = i / 576;
        int r = i - k * 576;
        int c = r / 9;
        int t = r - c * 9;
        unsigned v = (unsigned)w[i];
        g_wb[((0 * 9 + t) * 64 + k) * 64 + c] = (unsigned char)((v & 255u) ^ 0x80u);
        g_wb[((1 * 9 + t) * 64 + k) * 64 + c] = (unsigned char)(((v >> 8) & 255u) ^ 0x80u);
    } else {
        int k    = threadIdx.x >> 2;            // 4 threads per k
        int part = threadIdx.x & 3;
        int s0 = 0, s1 = 0;
        for (int j = part * 144; j < part * 144 + 144; ++j) {
            unsigned W = (unsigned)w[k * 576 + j];
            s0 += (int)(W & 255u);
            s1 += (int)((W >> 8) & 255u);
        }
        s0 += __shfl_xor(s0, 1); s0 += __shfl_xor(s0, 2);
        s1 += __shfl_xor(s1, 1); s1 += __shfl_xor(s1, 2);
        if (part == 0) {
            s0 -= 73728;                        // -128*576
            s1 -= 73728;
            unsigned ws = (unsigned)(s0 + 256 * s1);
            g_off[k] = (unsigned)bias[k] + 32896u * ws + 1082146816u * 576u;
        }
    }
}

// Pack one chunk: 60 halo pixels (6 rows x 10 cols) x 4 channel-groups,
// one quarter-pixel (16 channels) per thread.  IWB = iw of pcz==0 column.
// All math exec-uniform; only pk lanes touch LDS.
#define PACK_CHUNK(IWB, BUF) do {                                              \
    unsigned xv[16];                                                           \
    _Pragma("unroll")                                                          \
    for (int i_ = 0; i_ < 16; ++i_) xv[i_] = 0u;                               \
    const int iw_ = (IWB) + pcz;                                               \
    if (pk && rowok && (unsigned)iw_ < 56u) {                                  \
        const int* xp_ = x + xbase + ih * 56 + iw_;                            \
        _Pragma("unroll")                                                      \
        for (int i_ = 0; i_ < 16; ++i_)                                        \
            xv[i_] = (unsigned)xp_[(g * 16 + i_) * 3136];                      \
    }                                                                          \
    unsigned slo_ = 0, shi_ = 0, lo_[4], hi_[4];                               \
    _Pragma("unroll")                                                          \
    for (int u_ = 0; u_ < 4; ++u_) {                                           \
        unsigned t01_ = __builtin_amdgcn_perm(xv[4 * u_ + 1], xv[4 * u_ + 0], 0x05040100u); \
        unsigned t23_ = __builtin_amdgcn_perm(xv[4 * u_ + 3], xv[4 * u_ + 2], 0x05040100u); \
        unsigned lw_  = __builtin_amdgcn_perm(t23_, t01_, 0x06040200u);        \
        unsigned hw_  = __builtin_amdgcn_perm(t23_, t01_, 0x07050301u);        \
        slo_ = bsum(lw_, slo_);                                                \
        shi_ = bsum(hw_, shi_);                                                \
        lo_[u_] = lw_ ^ 0x80808080u;                                           \
        hi_[u_] = hw_ ^ 0x80808080u;                                           \
    }                                                                          \
    int s_ = (int)(slo_ + (shi_ << 8));                                        \
    s_ += __shfl_xor(s_, 1);                                                   \
    s_ += __shfl_xor(s_, 2);                                                   \
    if (pk) {                                                                  \
        unsigned char* ob_ = sx + (BUF) * CBUF + pr * CROW + pcz * LCOL + g * 16; \
        *(uint4*)(ob_)      = make_uint4(lo_[0], lo_[1], lo_[2], lo_[3]);      \
        *(uint4*)(ob_ + 64) = make_uint4(hi_[0], hi_[1], hi_[2], hi_[3]);      \
        if (g == 0) ss[BUF][pr][pcz] = s_ - 2105344;   /* -64*32896 */         \
    }                                                                          \
} while (0)

__global__ __launch_bounds__(256, 2) void secconv(const int* __restrict__ x,
                                                  int* __restrict__ out)
{
    __shared__ __align__(16) unsigned char sx[2 * CBUF];   // 17280 B
    __shared__ int ss[2][6][12];                           // S-plane per chunk

    const int tid  = threadIdx.x;
    const int blk  = blockIdx.x;                // 448 = 8 xcd * 56
    const int q    = blk >> 3;
    const int rg   = q % 14;                    // row-group of 4 output rows
    const int n    = (blk & 7) + 8 * (q / 14);
    const int wid  = tid >> 6;                  // ktile 0..3 -> k base wid*16
    const int lane = tid & 63;
    const int lm   = lane & 15;
    const int lq   = lane >> 4;
    const int r8   = lm >> 3;                   // pixel tile: 2 rows x 8 cols
    const int c8   = lm & 7;

    // pack task decode: 60 halo pixels (6 rows x 10 cols) x 4 channel-groups
    const int  pix   = tid >> 2;
    const int  g     = tid & 3;
    const int  pr    = pix / 10;
    const int  pcz   = pix - 10 * pr;
    const bool pk    = tid < 240;
    const int  ih    = 4 * rg - 1 + pr;
    const bool rowok = (unsigned)ih < 56u;
    const long xbase = (long)n * 64 * 3136;     // batch stride (symbolic!)

    // resident weight fragments for this wave's ktile: 2 limbs x 9 taps
    v4i wf[2][9];
#pragma unroll
    for (int l = 0; l < 2; ++l)
#pragma unroll
        for (int tp = 0; tp < 9; ++tp)
            wf[l][tp] = *(const v4i*)(g_wb +
                (((l * 9 + tp) * 64) + (wid * 16 + lm)) * 64 + lq * 16);
    unsigned offv[4];
#pragma unroll
    for (int r = 0; r < 4; ++r) offv[r] = g_off[wid * 16 + lq * 4 + r];

    // ---- prologue: pack chunk 0 into buffer 0 ----
    PACK_CHUNK(-1, 0);
    __syncthreads();

    for (int t = 0; t < 7; ++t) {
        const int cur = t & 1;

        // Q from the S-plane (5 col-sums shared across the 2 row-pairs)
        int cs[5];
#pragma unroll
        for (int j = 0; j < 5; ++j)
            cs[j] = ss[cur][r8 + j][c8] + ss[cur][r8 + j][c8 + 1] + ss[cur][r8 + j][c8 + 2];
        const unsigned qq0 = 32896u * (unsigned)(cs[0] + cs[1] + cs[2]);
        const unsigned qq1 = 32896u * (unsigned)(cs[2] + cs[3] + cs[4]);

        // 9-tap MFMA on chunk t (both row-pairs, 4 limb chains each)
        v4i a00[2] = {{0,0,0,0},{0,0,0,0}}, a01[2] = {{0,0,0,0},{0,0,0,0}};
        v4i a10[2] = {{0,0,0,0},{0,0,0,0}}, a11[2] = {{0,0,0,0},{0,0,0,0}};
        const unsigned char* cb = sx + cur * CBUF + r8 * CROW + c8 * LCOL + lq * 16;
        __builtin_amdgcn_s_setprio(1);
#pragma unroll
        for (int tap = 0; tap < 9; ++tap) {
            const int dr = tap / 3, dc = tap - 3 * (tap / 3);
            const unsigned char* pb = cb + dr * CROW + dc * LCOL;
            v4i bl0 = *(const v4i*)(pb);
            v4i bh0 = *(const v4i*)(pb + 64);
            v4i bl1 = *(const v4i*)(pb + 2 * CROW);
            v4i bh1 = *(const v4i*)(pb + 2 * CROW + 64);
            a00[0] = __builtin_amdgcn_mfma_i32_16x16x64_i8(wf[0][tap], bl0, a00[0], 0, 0, 0);
            a01[0] = __builtin_amdgcn_mfma_i32_16x16x64_i8(wf[0][tap], bh0, a01[0], 0, 0, 0);
            a10[0] = __builtin_amdgcn_mfma_i32_16x16x64_i8(wf[1][tap], bl0, a10[0], 0, 0, 0);
            a11[0] = __builtin_amdgcn_mfma_i32_16x16x64_i8(wf[1][tap], bh0, a11[0], 0, 0, 0);
            a00[1] = __builtin_amdgcn_mfma_i32_16x16x64_i8(wf[0][tap], bl1, a00[1], 0, 0, 0);
            a01[1] = __builtin_amdgcn_mfma_i32_16x16x64_i8(wf[0][tap], bh1, a01[1], 0, 0, 0);
            a10[1] = __builtin_amdgcn_mfma_i32_16x16x64_i8(wf[1][tap], bl1, a10[1], 0, 0, 0);
            a11[1] = __builtin_amdgcn_mfma_i32_16x16x64_i8(wf[1][tap], bh1, a11[1], 0, 0, 0);
        }
        __builtin_amdgcn_s_setprio(0);

        // epilogue stores (8 cols of this chunk, both row-pairs, 16 k)
#pragma unroll
        for (int ph = 0; ph < 2; ++ph) {
            const unsigned qq = ph ? qq1 : qq0;
            const long ob = ((long)n * 64 + wid * 16 + lq * 4) * 3136
                          + (long)(4 * rg + 2 * ph + r8) * 56 + 8 * t + c8;
#pragma unroll
            for (int r = 0; r < 4; ++r) {
                unsigned val = (unsigned)a00[ph][r]
                             + (((unsigned)a01[ph][r] + (unsigned)a10[ph][r]) << 8)
                             + ((unsigned)a11[ph][r] << 16)
                             + qq + offv[r];
                out[ob + (long)r * 3136] = (int)val;
            }
        }

        // pack chunk t+1 into the other buffer (loads + pack in one place;
        // compiler may hoist the global loads above the MFMAs)
        if (t < 6) PACK_CHUNK(8 * (t + 1) - 1, cur ^ 1);
        __syncthreads();
    }
}

extern "C" void kernel_launch(void* const* d_in, const int* in_sizes, int n_in,
                              void* d_out, int out_size, void* d_ws, size_t ws_size,
                              hipStream_t stream)
{
    const int* x    = (const int*)d_in[0];
    const int* w    = (const int*)d_in[1];
    const int* bias = (const int*)d_in[2];
    int* out        = (int*)d_out;

    packw  <<<dim3(145), dim3(256), 0, stream>>>(w, bias);
    secconv<<<dim3(448), dim3(256), 0, stream>>>(x, out);
}

// Round 6
// 106.704 us; speedup vs baseline: 1.0125x; 1.0125x over previous
//
#include <hip/hip_runtime.h>

// SecConv2d over Z_{2^32} via i8 MFMA, 4-chain biased-operand scheme (exact).
//   s(x) = x_byte - 128 per limb  => X = s(al) + 256*s(ah) + 32896
//   s(w) likewise                 => W = s0 + 256*s1 + 32896
//   out = P00 + (P01+P10)<<8 + P11<<16 + 32896*Q[p] + K[k]   (mod 2^32)
//   Q = 3x3 box sum of S[p], S[p] = sum_c (X_true - 32896) (border cells are
//   bytes 0x80 == s=-128 -> uniformly "interior with x=0", exact).
//
// R15 = R14 + two latency fixes driven by rocprof (VGPR=84, MfmaUtil=12%):
//  (a) wf residency pin: opaque asm "+v" on each weight fragment after load.
//      R14's compiler re-loaded wf from g_wb inside the tap loop (72-reg
//      array not resident at VGPR_Count=84) -> global-load latency inside
//      the MFMA cluster.
//  (b) T14 issue-early/write-late pack: PACK_LOAD at top of iteration
//      (before Q/MFMA), PACK_FINISH after the epilogue stores. R14 issued
//      loads right before the barrier -> ~900 cy exposed per chunk.

typedef int v4i __attribute__((ext_vector_type(4)));

#define LCOL 144               // LDS col stride (128 B payload + 16 pad)
#define CROW (10 * LCOL)       // 1440 B per halo row within a chunk
#define CBUF (6 * CROW)        // 8640 B per chunk buffer

__device__ __align__(16) unsigned char g_wb[2 * 9 * 64 * 64];
__device__ unsigned g_off[64];

static __device__ __forceinline__ unsigned bsum(unsigned v, unsigned acc) {
#if __has_builtin(__builtin_amdgcn_sad_u8)
    return __builtin_amdgcn_sad_u8(v, 0u, acc);
#else
    return acc + (v & 0xFFu) + ((v >> 8) & 0xFFu) + ((v >> 16) & 0xFFu) + (v >> 24);
#endif
}

__global__ __launch_bounds__(256) void packw(const int* __restrict__ w,
                                             const int* __restrict__ bias) {
    int blk = blockIdx.x;
    if (blk < 144) {
        int i = blk * 256 + threadIdx.x;        // [k][c][t] flat, 36864
        if (i >= 64 * 64 * 9) return;
        int k = i / 576;
        int r = i - k * 576;
        int c = r / 9;
        int t = r - c * 9;
        unsigned v = (unsigned)w[i];
        g_wb[((0 * 9 + t) * 64 + k) * 64 + c] = (unsigned char)((v & 255u) ^ 0x80u);
        g_wb[((1 * 9 + t) * 64 + k) * 64 + c] = (unsigned char)(((v >> 8) & 255u) ^ 0x80u);
    } else {
        int k    = threadIdx.x >> 2;            // 4 threads per k
        int part = threadIdx.x & 3;
        int s0 = 0, s1 = 0;
        for (int j = part * 144; j < part * 144 + 144; ++j) {
            unsigned W = (unsigned)w[k * 576 + j];
            s0 += (int)(W & 255u);
            s1 += (int)((W >> 8) & 255u);
        }
        s0 += __shfl_xor(s0, 1); s0 += __shfl_xor(s0, 2);
        s1 += __shfl_xor(s1, 1); s1 += __shfl_xor(s1, 2);
        if (part == 0) {
            s0 -= 73728;                        // -128*576
            s1 -= 73728;
            unsigned ws = (unsigned)(s0 + 256 * s1);
            g_off[k] = (unsigned)bias[k] + 32896u * ws + 1082146816u * 576u;
        }
    }
}

// Issue the 16 global loads of one quarter-pixel pack task into XV.
#define PACK_LOAD(XV, IWB, EN) do {                                            \
    _Pragma("unroll")                                                          \
    for (int i_ = 0; i_ < 16; ++i_) XV[i_] = 0u;                               \
    const int iw_ = (IWB) + pcz;                                               \
    if ((EN) && pk && rowok && (unsigned)iw_ < 56u) {                          \
        const int* xp_ = x + xbase + ih * 56 + iw_;                            \
        _Pragma("unroll")                                                      \
        for (int i_ = 0; i_ < 16; ++i_)                                        \
            XV[i_] = (unsigned)xp_[(g * 16 + i_) * 3136];                      \
    }                                                                          \
} while (0)

// Finish the pack: transpose to bytes, bias, LDS write, S-plane reduce.
// All math exec-uniform; only pk lanes touch LDS.
#define PACK_FINISH(XV, BUF) do {                                              \
    unsigned slo_ = 0, shi_ = 0, lo_[4], hi_[4];                               \
    _Pragma("unroll")                                                          \
    for (int u_ = 0; u_ < 4; ++u_) {                                           \
        unsigned t01_ = __builtin_amdgcn_perm(XV[4 * u_ + 1], XV[4 * u_ + 0], 0x05040100u); \
        unsigned t23_ = __builtin_amdgcn_perm(XV[4 * u_ + 3], XV[4 * u_ + 2], 0x05040100u); \
        unsigned lw_  = __builtin_amdgcn_perm(t23_, t01_, 0x06040200u);        \
        unsigned hw_  = __builtin_amdgcn_perm(t23_, t01_, 0x07050301u);        \
        slo_ = bsum(lw_, slo_);                                                \
        shi_ = bsum(hw_, shi_);                                                \
        lo_[u_] = lw_ ^ 0x80808080u;                                           \
        hi_[u_] = hw_ ^ 0x80808080u;                                           \
    }                                                                          \
    int s_ = (int)(slo_ + (shi_ << 8));                                        \
    s_ += __shfl_xor(s_, 1);                                                   \
    s_ += __shfl_xor(s_, 2);                                                   \
    if (pk) {                                                                  \
        unsigned char* ob_ = sx + (BUF) * CBUF + pr * CROW + pcz * LCOL + g * 16; \
        *(uint4*)(ob_)      = make_uint4(lo_[0], lo_[1], lo_[2], lo_[3]);      \
        *(uint4*)(ob_ + 64) = make_uint4(hi_[0], hi_[1], hi_[2], hi_[3]);      \
        if (g == 0) ss[BUF][pr][pcz] = s_ - 2105344;   /* -64*32896 */         \
    }                                                                          \
} while (0)

__global__ __launch_bounds__(256, 2) void secconv(const int* __restrict__ x,
                                                  int* __restrict__ out)
{
    __shared__ __align__(16) unsigned char sx[2 * CBUF];   // 17280 B
    __shared__ int ss[2][6][12];                           // S-plane per chunk

    const int tid  = threadIdx.x;
    const int blk  = blockIdx.x;                // 448 = 8 xcd * 56
    const int q    = blk >> 3;
    const int rg   = q % 14;                    // row-group of 4 output rows
    const int n    = (blk & 7) + 8 * (q / 14);
    const int wid  = tid >> 6;                  // ktile 0..3 -> k base wid*16
    const int lane = tid & 63;
    const int lm   = lane & 15;
    const int lq   = lane >> 4;
    const int r8   = lm >> 3;                   // pixel tile: 2 rows x 8 cols
    const int c8   = lm & 7;

    // pack task decode: 60 halo pixels (6 rows x 10 cols) x 4 channel-groups
    const int  pix   = tid >> 2;
    const int  g     = tid & 3;
    const int  pr    = pix / 10;
    const int  pcz   = pix - 10 * pr;
    const bool pk    = tid < 240;
    const int  ih    = 4 * rg - 1 + pr;
    const bool rowok = (unsigned)ih < 56u;
    const long xbase = (long)n * 64 * 3136;     // batch stride (symbolic!)

    // resident weight fragments for this wave's ktile: 2 limbs x 9 taps
    v4i wf[2][9];
#pragma unroll
    for (int l = 0; l < 2; ++l)
#pragma unroll
        for (int tp = 0; tp < 9; ++tp)
            wf[l][tp] = *(const v4i*)(g_wb +
                (((l * 9 + tp) * 64) + (wid * 16 + lm)) * 64 + lq * 16);
    // Pin residency: opaque asm -> LLVM cannot rematerialize these from
    // memory inside the tap loop (R14 reloaded them: VGPR=84, MfmaUtil=12%).
#pragma unroll
    for (int l = 0; l < 2; ++l)
#pragma unroll
        for (int tp = 0; tp < 9; ++tp)
            asm volatile("" : "+v"(wf[l][tp]));

    unsigned offv[4];
#pragma unroll
    for (int r = 0; r < 4; ++r) offv[r] = g_off[wid * 16 + lq * 4 + r];

    // ---- prologue: pack chunk 0 into buffer 0 ----
    {
        unsigned xv[16];
        PACK_LOAD(xv, -1, true);
        PACK_FINISH(xv, 0);
    }
    __syncthreads();

    for (int t = 0; t < 7; ++t) {
        const int cur = t & 1;

        // phase A: issue chunk t+1 loads now; they complete under the MFMAs
        unsigned xv[16];
        PACK_LOAD(xv, 8 * (t + 1) - 1, t < 6);

        // Q from the S-plane (5 col-sums shared across the 2 row-pairs)
        int cs[5];
#pragma unroll
        for (int j = 0; j < 5; ++j)
            cs[j] = ss[cur][r8 + j][c8] + ss[cur][r8 + j][c8 + 1] + ss[cur][r8 + j][c8 + 2];
        const unsigned qq0 = 32896u * (unsigned)(cs[0] + cs[1] + cs[2]);
        const unsigned qq1 = 32896u * (unsigned)(cs[2] + cs[3] + cs[4]);

        // 9-tap MFMA on chunk t (both row-pairs, 4 limb chains each)
        v4i a00[2] = {{0,0,0,0},{0,0,0,0}}, a01[2] = {{0,0,0,0},{0,0,0,0}};
        v4i a10[2] = {{0,0,0,0},{0,0,0,0}}, a11[2] = {{0,0,0,0},{0,0,0,0}};
        const unsigned char* cb = sx + cur * CBUF + r8 * CROW + c8 * LCOL + lq * 16;
        __builtin_amdgcn_s_setprio(1);
#pragma unroll
        for (int tap = 0; tap < 9; ++tap) {
            const int dr = tap / 3, dc = tap - 3 * (tap / 3);
            const unsigned char* pb = cb + dr * CROW + dc * LCOL;
            v4i bl0 = *(const v4i*)(pb);
            v4i bh0 = *(const v4i*)(pb + 64);
            v4i bl1 = *(const v4i*)(pb + 2 * CROW);
            v4i bh1 = *(const v4i*)(pb + 2 * CROW + 64);
            a00[0] = __builtin_amdgcn_mfma_i32_16x16x64_i8(wf[0][tap], bl0, a00[0], 0, 0, 0);
            a01[0] = __builtin_amdgcn_mfma_i32_16x16x64_i8(wf[0][tap], bh0, a01[0], 0, 0, 0);
            a10[0] = __builtin_amdgcn_mfma_i32_16x16x64_i8(wf[1][tap], bl0, a10[0], 0, 0, 0);
            a11[0] = __builtin_amdgcn_mfma_i32_16x16x64_i8(wf[1][tap], bh0, a11[0], 0, 0, 0);
            a00[1] = __builtin_amdgcn_mfma_i32_16x16x64_i8(wf[0][tap], bl1, a00[1], 0, 0, 0);
            a01[1] = __builtin_amdgcn_mfma_i32_16x16x64_i8(wf[0][tap], bh1, a01[1], 0, 0, 0);
            a10[1] = __builtin_amdgcn_mfma_i32_16x16x64_i8(wf[1][tap], bl1, a10[1], 0, 0, 0);
            a11[1] = __builtin_amdgcn_mfma_i32_16x16x64_i8(wf[1][tap], bh1, a11[1], 0, 0, 0);
        }
        __builtin_amdgcn_s_setprio(0);

        // epilogue stores (8 cols of this chunk, both row-pairs, 16 k)
#pragma unroll
        for (int ph = 0; ph < 2; ++ph) {
            const unsigned qq = ph ? qq1 : qq0;
            const long ob = ((long)n * 64 + wid * 16 + lq * 4) * 3136
                          + (long)(4 * rg + 2 * ph + r8) * 56 + 8 * t + c8;
#pragma unroll
            for (int r = 0; r < 4; ++r) {
                unsigned val = (unsigned)a00[ph][r]
                             + (((unsigned)a01[ph][r] + (unsigned)a10[ph][r]) << 8)
                             + ((unsigned)a11[ph][r] << 16)
                             + qq + offv[r];
                out[ob + (long)r * 3136] = (int)val;
            }
        }

        // phase E: write-late pack of chunk t+1 into the other buffer
        if (t < 6) PACK_FINISH(xv, cur ^ 1);
        __syncthreads();
    }
}

extern "C" void kernel_launch(void* const* d_in, const int* in_sizes, int n_in,
                              void* d_out, int out_size, void* d_ws, size_t ws_size,
                              hipStream_t stream)
{
    const int* x    = (const int*)d_in[0];
    const int* w    = (const int*)d_in[1];
    const int* bias = (const int*)d_in[2];
    int* out        = (int*)d_out;

    packw  <<<dim3(145), dim3(256), 0, stream>>>(w, bias);
    secconv<<<dim3(448), dim3(256), 0, stream>>>(x, out);
}

// Round 7
// 99.535 us; speedup vs baseline: 1.0854x; 1.0720x over previous
//
#include <hip/hip_runtime.h>

// SecConv2d over Z_{2^32} via i8 MFMA, 4-chain biased-operand scheme (exact).
//   s(x) = x_byte - 128 per limb  => X = s(al) + 256*s(ah) + 32896
//   s(w) likewise                 => W = s0 + 256*s1 + 32896
//   out = P00 + (P01+P10)<<8 + P11<<16 + 32896*Q[p] + K[k]   (mod 2^32)
//   Q = 3x3 box sum of S[p], S[p] = sum_c (X_true - 32896) (border cells are
//   bytes 0x80 == s=-128 -> uniformly "interior with x=0", exact).
//
// R16: back to the proven R9 base (full 6x58 halo staged once, waves =
// ktile-pair x row-pair, single barrier). New pack-v3, driven by the issue
// model (R9 pack ~5 issue-slots/dword: dword loads + 64-bit addr adds):
//   task (pr, pq, c4) = 4 consecutive PIXELS (dwordx4, x is row-contiguous)
//   x 16 channels; channel offsets are wave-uniform -> SGPR saddr, per-lane
//   voff computed once. Same perm tree; LDS bytes identical to R9; S via
//   quad shfl_xor(1,2). ~2.1 slots/dword, 336 balanced tasks.
// Plus T5 s_setprio around the MFMA cluster. MFMA/Q/epilogue = R9 verbatim.

typedef int v4i __attribute__((ext_vector_type(4)));

#define LCOL 144               // LDS col stride (128 B payload + 16 pad)
#define LROW (58 * LCOL)       // 8352 B per LDS halo row

__device__ __align__(16) unsigned char g_wb[2 * 9 * 64 * 64];
__device__ unsigned g_off[64];

static __device__ __forceinline__ unsigned bsum(unsigned v, unsigned acc) {
#if __has_builtin(__builtin_amdgcn_sad_u8)
    return __builtin_amdgcn_sad_u8(v, 0u, acc);
#else
    return acc + (v & 0xFFu) + ((v >> 8) & 0xFFu) + ((v >> 16) & 0xFFu) + (v >> 24);
#endif
}

__global__ __launch_bounds__(256) void packw(const int* __restrict__ w,
                                             const int* __restrict__ bias) {
    int blk = blockIdx.x;
    if (blk < 144) {
        int i = blk * 256 + threadIdx.x;        // [k][c][t] flat, 36864
        if (i >= 64 * 64 * 9) return;
        int k = i / 576;
        int r = i - k * 576;
        int c = r / 9;
        int t = r - c * 9;
        unsigned v = (unsigned)w[i];
        g_wb[((0 * 9 + t) * 64 + k) * 64 + c] = (unsigned char)((v & 255u) ^ 0x80u);
        g_wb[((1 * 9 + t) * 64 + k) * 64 + c] = (unsigned char)(((v >> 8) & 255u) ^ 0x80u);
    } else {
        int k    = threadIdx.x >> 2;            // 4 threads per k
        int part = threadIdx.x & 3;
        int s0 = 0, s1 = 0;
        for (int j = part * 144; j < part * 144 + 144; ++j) {
            unsigned W = (unsigned)w[k * 576 + j];
            s0 += (int)(W & 255u);
            s1 += (int)((W >> 8) & 255u);
        }
        s0 += __shfl_xor(s0, 1); s0 += __shfl_xor(s0, 2);
        s1 += __shfl_xor(s1, 1); s1 += __shfl_xor(s1, 2);
        if (part == 0) {
            s0 -= 73728;                        // -128*576
            s1 -= 73728;
            unsigned ws = (unsigned)(s0 + 256 * s1);
            g_off[k] = (unsigned)bias[k] + 32896u * ws + 1082146816u * 576u;
        }
    }
}

__global__ __launch_bounds__(256, 2) void secconv(const int* __restrict__ x,
                                                  int* __restrict__ out)
{
    __shared__ unsigned char sx[6 * LROW];      // 50112 B
    __shared__ int ss[6 * 58];                  // S-plane, 6 halo rows

    const int tid  = threadIdx.x;
    const int blk  = blockIdx.x;                // 448 = 8 xcd * 56
    const int q    = blk >> 3;
    const int rg   = q % 14;                    // row-group of 4 output rows
    const int n    = (blk & 7) + 8 * (q / 14);
    const int wid  = tid >> 6;
    const int lane = tid & 63;
    const int lm   = lane & 15;
    const int lq   = lane >> 4;
    const int kp   = wid & 1;                   // ktile-pair -> k base kp*32
    const int ph   = wid >> 1;                  // row-pair within the 4 rows
    const int kbase = kp * 32;

    // ---- border fill: halo cols pc=0,57 (12 cells) + border row if any ----
    const uint4 fillv = make_uint4(0x80808080u, 0x80808080u, 0x80808080u, 0x80808080u);
    if (tid < 96) {
        const int cell = tid >> 3, i = tid & 7;
        const int pr = cell >> 1, pc = (cell & 1) * 57;
        *(uint4*)(sx + pr * LROW + pc * LCOL + i * 16) = fillv;
        if (i == 0) ss[pr * 58 + pc] = -2105344;     // -64*32896
    }
    const int brow = (rg == 0) ? 0 : (rg == 13 ? 5 : -1);
    if (brow >= 0) {
        for (int j = tid; j < 464; j += 256) {       // 58 cells x 8 stores
            const int cell = j >> 3, i = j & 7;
            *(uint4*)(sx + brow * LROW + cell * LCOL + i * 16) = fillv;
            if (i == 0) ss[brow * 58 + cell] = -2105344;
        }
    }

    // ---- pack v3: 336 tasks (pr 0..5, pq 0..13, c4 0..3) ----
    // task = 4 consecutive pixels (iw = 4pq..4pq+3) x 16 channels (c4*16..+15)
    const int* bp = x + (long)n * 64 * 3136;    // uniform batch base -> SGPR
    for (int task = tid; task < 336; task += 256) {
        const int pr = task / 56;
        const int rr = task - pr * 56;
        const int pq = rr >> 2;
        const int c4 = rr & 3;
        const int ih = 4 * rg - 1 + pr;
        if ((unsigned)ih < 56u) {                    // interior row
            const int voff = c4 * 16 * 3136 + ih * 56 + pq * 4;   // per-lane, once
            unsigned slo[4] = {0, 0, 0, 0}, shi[4] = {0, 0, 0, 0};
            unsigned lov[4][4], hiv[4][4];           // [cb][px]
#pragma unroll
            for (int cb = 0; cb < 4; ++cb) {         // ch = c4*16 + cb*4 + j
                v4i q0 = *(const v4i*)(bp + (cb * 4 + 0) * 3136 + voff);
                v4i q1 = *(const v4i*)(bp + (cb * 4 + 1) * 3136 + voff);
                v4i q2 = *(const v4i*)(bp + (cb * 4 + 2) * 3136 + voff);
                v4i q3 = *(const v4i*)(bp + (cb * 4 + 3) * 3136 + voff);
#pragma unroll
                for (int p = 0; p < 4; ++p) {        // pixel within quad
                    unsigned t01 = __builtin_amdgcn_perm((unsigned)q1[p], (unsigned)q0[p], 0x05040100u);
                    unsigned t23 = __builtin_amdgcn_perm((unsigned)q3[p], (unsigned)q2[p], 0x05040100u);
                    unsigned lw  = __builtin_amdgcn_perm(t23, t01, 0x06040200u);
                    unsigned hw  = __builtin_amdgcn_perm(t23, t01, 0x07050301u);
                    slo[p] = bsum(lw, slo[p]);
                    shi[p] = bsum(hw, shi[p]);
                    lov[cb][p] = lw ^ 0x80808080u;
                    hiv[cb][p] = hw ^ 0x80808080u;
                }
            }
            // LDS: pixel pc = pq*4 + 1 + p; byte lane = channel; identical to R9
            unsigned char* ob = sx + pr * LROW + (pq * 4 + 1) * LCOL + c4 * 16;
#pragma unroll
            for (int p = 0; p < 4; ++p) {
                *(uint4*)(ob + p * LCOL)      = make_uint4(lov[0][p], lov[1][p], lov[2][p], lov[3][p]);
                *(uint4*)(ob + p * LCOL + 64) = make_uint4(hiv[0][p], hiv[1][p], hiv[2][p], hiv[3][p]);
            }
            // S: sum the 4 c4-lanes of this quad (lanes differ only in bits 0..1)
#pragma unroll
            for (int p = 0; p < 4; ++p) {
                int s = (int)(slo[p] + (shi[p] << 8));
                s += __shfl_xor(s, 1);
                s += __shfl_xor(s, 2);
                if (c4 == 0) ss[pr * 58 + pq * 4 + 1 + p] = s - 2105344;
            }
        }
    }

    // ---- resident weight fragments: 2 ktiles x 2 limbs x 9 taps ----
    v4i wf[2][2][9];
#pragma unroll
    for (int kt = 0; kt < 2; ++kt)
#pragma unroll
        for (int l = 0; l < 2; ++l)
#pragma unroll
            for (int t = 0; t < 9; ++t)
                wf[kt][l][t] = *(const v4i*)(g_wb +
                    ((l * 9 + t) * 64 + (kbase + kt * 16 + lm)) * 64 + lq * 16);
    unsigned offv[2][4];
#pragma unroll
    for (int kt = 0; kt < 2; ++kt)
#pragma unroll
        for (int r = 0; r < 4; ++r)
            offv[kt][r] = g_off[kbase + kt * 16 + lq * 4 + r];

    __syncthreads();

    const int r8 = lm >> 3, c8 = lm & 7;        // pixel tile: 2 rows x 8 cols
    const int lrow = 2 * ph + r8;               // LDS halo row of this lane
    const unsigned char* lbase = sx + lrow * LROW + c8 * LCOL + lq * 16;

    for (int t = 0; t < 7; ++t) {               // 7 col-groups of 8
        const unsigned char* tb = lbase + t * 8 * LCOL;
        v4i a00[2] = {{0,0,0,0},{0,0,0,0}}, a01[2] = {{0,0,0,0},{0,0,0,0}};
        v4i a10[2] = {{0,0,0,0},{0,0,0,0}}, a11[2] = {{0,0,0,0},{0,0,0,0}};
        __builtin_amdgcn_s_setprio(1);
#pragma unroll
        for (int tap = 0; tap < 9; ++tap) {
            const int dr = tap / 3, dc = tap - (tap / 3) * 3;
            const unsigned char* pp = tb + dr * LROW + dc * LCOL;
            v4i bl = *(const v4i*)(pp);
            v4i bh = *(const v4i*)(pp + 64);
#pragma unroll
            for (int kt = 0; kt < 2; ++kt) {
                a00[kt] = __builtin_amdgcn_mfma_i32_16x16x64_i8(wf[kt][0][tap], bl, a00[kt], 0, 0, 0);
                a01[kt] = __builtin_amdgcn_mfma_i32_16x16x64_i8(wf[kt][0][tap], bh, a01[kt], 0, 0, 0);
                a10[kt] = __builtin_amdgcn_mfma_i32_16x16x64_i8(wf[kt][1][tap], bl, a10[kt], 0, 0, 0);
                a11[kt] = __builtin_amdgcn_mfma_i32_16x16x64_i8(wf[kt][1][tap], bh, a11[kt], 0, 0, 0);
            }
        }
        __builtin_amdgcn_s_setprio(0);

        const int pc = t * 8 + c8;
        int Q = 0;
#pragma unroll
        for (int dr = 0; dr < 3; ++dr)
#pragma unroll
            for (int dc = 0; dc < 3; ++dc)
                Q += ss[(lrow + dr) * 58 + pc + dc];
        const unsigned qq = 32896u * (unsigned)Q;

        const long pix = (long)(4 * rg + lrow) * 56 + pc;
#pragma unroll
        for (int kt = 0; kt < 2; ++kt) {
            const long ob = ((long)n * 64 + kbase + kt * 16 + lq * 4) * 3136 + pix;
#pragma unroll
            for (int r = 0; r < 4; ++r) {
                unsigned val = (unsigned)a00[kt][r]
                             + (((unsigned)a01[kt][r] + (unsigned)a10[kt][r]) << 8)
                             + ((unsigned)a11[kt][r] << 16)
                             + qq + offv[kt][r];
                out[ob + (long)r * 3136] = (int)val;
            }
        }
    }
}

extern "C" void kernel_launch(void* const* d_in, const int* in_sizes, int n_in,
                              void* d_out, int out_size, void* d_ws, size_t ws_size,
                              hipStream_t stream)
{
    const int* x    = (const int*)d_in[0];
    const int* w    = (const int*)d_in[1];
    const int* bias = (const int*)d_in[2];
    int* out        = (int*)d_out;

    packw  <<<dim3(145), dim3(256), 0, stream>>>(w, bias);
    secconv<<<dim3(448), dim3(256), 0, stream>>>(x, out);
}